// Round 6
// baseline (461.361 us; speedup 1.0000x reference)
//
#include <hip/hip_runtime.h>
#include <math.h>

// Problem constants (VQ2): B=16384, D_IN=512, H=64, C=256, K=2048
#define NB 16384
#define NDIN 512
#define NH 64
#define NC 256
#define NK 2048

typedef __bf16 bf16;
typedef __bf16 bf16x4 __attribute__((ext_vector_type(4)));
typedef __bf16 bf16x8 __attribute__((ext_vector_type(8)));
typedef float f32x4 __attribute__((ext_vector_type(4)));

__device__ __forceinline__ void gload_lds16(const bf16* g, bf16* l) {
  __builtin_amdgcn_global_load_lds(
      (const __attribute__((address_space(1))) void*)g,
      (__attribute__((address_space(3))) void*)l, 16, 0, 0);
}

// ---------------------------------------------------------------------------
// Elementwise fp32 -> bf16 cast (n4 = count/4)
// ---------------------------------------------------------------------------
__global__ __launch_bounds__(256) void cast_f2b(const float* __restrict__ in,
                                                bf16* __restrict__ out, int n4) {
  int i = blockIdx.x * 256 + threadIdx.x;
  if (i >= n4) return;
  float4 v = ((const float4*)in)[i];
  bf16x4 o;
  o[0] = (bf16)v.x; o[1] = (bf16)v.y; o[2] = (bf16)v.z; o[3] = (bf16)v.w;
  ((bf16x4*)out)[i] = o;
}

// ---------------------------------------------------------------------------
// W [K][N] fp32 -> Wt [N][K] bf16 (tiny matrices, coalesced writes)
// ---------------------------------------------------------------------------
__global__ __launch_bounds__(256) void transpose_cast(const float* __restrict__ W,
                                                      bf16* __restrict__ Wt, int K, int N) {
  int i = blockIdx.x * 256 + threadIdx.x;
  if (i >= K * N) return;
  int n = i / K, k = i - n * K;
  Wt[i] = (bf16)W[k * N + n];
}

// ---------------------------------------------------------------------------
// protos fp32 [NK][NC] -> bf16 + pn (norm of the ROUNDED values, one wave/row)
// ---------------------------------------------------------------------------
__global__ __launch_bounds__(256) void cast_protos(const float* __restrict__ P,
                                                   bf16* __restrict__ Pb,
                                                   float* __restrict__ pn) {
  int wave = (int)((blockIdx.x * 256 + threadIdx.x) >> 6);
  int lane = threadIdx.x & 63;
  if (wave >= NK) return;
  float4 v = ((const float4*)(P + (size_t)wave * NC))[lane];
  bf16x4 o;
  o[0] = (bf16)v.x; o[1] = (bf16)v.y; o[2] = (bf16)v.z; o[3] = (bf16)v.w;
  ((bf16x4*)(Pb + (size_t)wave * NC))[lane] = o;
  float s = 0.f;
#pragma unroll
  for (int j = 0; j < 4; ++j) {
    float f = (float)o[j];
    s = fmaf(f, f, s);
  }
  for (int off = 32; off > 0; off >>= 1) s += __shfl_xor(s, off);
  if (lane == 0) pn[wave] = s;
}

// ---------------------------------------------------------------------------
// Row squared-norms of bf16 [rows][NC]; one wave per row.
// ---------------------------------------------------------------------------
__global__ __launch_bounds__(256) void rownorm_bf(const bf16* __restrict__ X,
                                                  float* __restrict__ out, int rows) {
  int wave = (int)((blockIdx.x * 256 + threadIdx.x) >> 6);
  int lane = threadIdx.x & 63;
  if (wave >= rows) return;
  bf16x4 v = ((const bf16x4*)(X + (size_t)wave * NC))[lane];
  float s = 0.f;
#pragma unroll
  for (int j = 0; j < 4; ++j) {
    float f = (float)v[j];
    s = fmaf(f, f, s);
  }
  for (int off = 32; off > 0; off >>= 1) s += __shfl_xor(s, off);
  if (lane == 0) out[wave] = s;
}

// ---------------------------------------------------------------------------
// MLP MFMA GEMM: out_bf16 = act(A @ Bt^T + bias)
// ---------------------------------------------------------------------------
template <int RELU>
__global__ __launch_bounds__(256) void mfma_mlp(const bf16* __restrict__ A,
                                                const bf16* __restrict__ Bt,
                                                const float* __restrict__ bias,
                                                bf16* __restrict__ out,
                                                int M, int K, int N) {
  __shared__ __align__(16) bf16 As[64 * 32];
  __shared__ __align__(16) bf16 Bs[64 * 32];
  const int t = threadIdx.x;
  const int w = t >> 6, lane = t & 63;
  const int bm = blockIdx.x * 64, bn = blockIdx.y * 64;
  const int lm = lane & 15, kq = lane >> 4;
  const int r = t >> 2, seg = t & 3;
  f32x4 acc[4] = {};
  for (int k0 = 0; k0 < K; k0 += 32) {
    __syncthreads();
    *(uint4*)&As[r * 32 + seg * 8] = *(const uint4*)&A[(size_t)(bm + r) * K + k0 + seg * 8];
    *(uint4*)&Bs[r * 32 + seg * 8] = *(const uint4*)&Bt[(size_t)(bn + r) * K + k0 + seg * 8];
    __syncthreads();
    bf16x8 bfr = *(const bf16x8*)&Bs[(w * 16 + lm) * 32 + kq * 8];
#pragma unroll
    for (int mi = 0; mi < 4; ++mi) {
      bf16x8 afr = *(const bf16x8*)&As[(mi * 16 + lm) * 32 + kq * 8];
      acc[mi] = __builtin_amdgcn_mfma_f32_16x16x32_bf16(afr, bfr, acc[mi], 0, 0, 0);
    }
  }
  const int col = bn + w * 16 + lm;
  const float bv = bias[col];
#pragma unroll
  for (int mi = 0; mi < 4; ++mi) {
#pragma unroll
    for (int rg = 0; rg < 4; ++rg) {
      float v = acc[mi][rg] + bv;
      if (RELU) v = fmaxf(v, 0.f);
      out[(size_t)(bm + mi * 16 + kq * 4 + rg) * N + col] = (bf16)v;
    }
  }
}

// ---------------------------------------------------------------------------
// Fused VQ kernel: replaces gemm_S + row_pass. S matrix never materialized.
// Grid = 256 blocks (1/CU), block = 64 rows. A-panel (64x256 bf16 = 32KB)
// resident in LDS; protos streamed in 32-col tiles (16KB, double-buffered).
// Phase 1: GEMM + online per-row (max, Z, argmax(s+gumbel)) in registers.
// Gather: out rows = protos[argmax]. Phase 2: GEMM recompute (bitwise-equal
// accumulation order) -> probs/colsums -> per-wave partials pp/pl.
// ---------------------------------------------------------------------------
__global__ __launch_bounds__(256) void fused_vq(
    const bf16* __restrict__ A,       // mub [NB][NC]
    const bf16* __restrict__ Bt,      // pb  [NK][NC]
    const float* __restrict__ rn, const float* __restrict__ pn,
    const float* __restrict__ gumbel, const float* __restrict__ protos,
    float* __restrict__ out, float* __restrict__ pp, float* __restrict__ pl) {
  __shared__ __align__(16) bf16 Al[8 * 64 * 32];     // 32KB [kc][row][k]
  __shared__ __align__(16) bf16 Bl[2][8 * 32 * 32];  // 2 x 16KB [kc][pr][k]
  const int t = threadIdx.x;
  const int w = t >> 6, lane = t & 63;
  const int lm = lane & 15, kq = lane >> 4;
  const int rbase = blockIdx.x * 64;

  // stage whole A panel + B tile 0
#pragma unroll
  for (int i = 0; i < 8; ++i) {
    int c = i * 256 + t, rc = c & 255;
    gload_lds16(&A[(size_t)(rbase + (rc >> 2)) * NC + (c >> 8) * 32 + (rc & 3) * 8],
                &Al[c * 8]);
  }
#pragma unroll
  for (int i = 0; i < 4; ++i) {
    int c = i * 256 + t, rc = c & 127;
    gload_lds16(&Bt[(size_t)(rc >> 2) * NC + (c >> 7) * 32 + (rc & 3) * 8],
                &Bl[0][c * 8]);
  }
  float rnv[4];
#pragma unroll
  for (int rg = 0; rg < 4; ++rg) rnv[rg] = rn[rbase + w * 16 + kq * 4 + rg];
  __syncthreads();

  float m_[4] = {-INFINITY, -INFINITY, -INFINITY, -INFINITY};
  float Z_[4] = {0.f, 0.f, 0.f, 0.f};
  float bv_[4] = {-INFINITY, -INFINITY, -INFINITY, -INFINITY};
  int bi_[4] = {0x7fffffff, 0x7fffffff, 0x7fffffff, 0x7fffffff};

// one GEMM tile: 8 kc-subtiles, 2 MFMA each -> acc0 (cols lm) acc1 (cols 16+lm)
#define FV_MMA(CUR)                                                              \
  f32x4 acc0 = {}, acc1 = {};                                                    \
  _Pragma("unroll") for (int kc = 0; kc < 8; ++kc) {                             \
    bf16x8 af = *(const bf16x8*)&Al[(kc * 64 + w * 16 + lm) * 32 + kq * 8];      \
    bf16x8 b0 = *(const bf16x8*)&Bl[CUR][(kc * 32 + lm) * 32 + kq * 8];          \
    bf16x8 b1 = *(const bf16x8*)&Bl[CUR][(kc * 32 + 16 + lm) * 32 + kq * 8];     \
    acc0 = __builtin_amdgcn_mfma_f32_16x16x32_bf16(af, b0, acc0, 0, 0, 0);       \
    acc1 = __builtin_amdgcn_mfma_f32_16x16x32_bf16(af, b1, acc1, 0, 0, 0);       \
  }

#define FV_STAGE(NT, DST)                                                        \
  if ((NT) < 64) {                                                               \
    _Pragma("unroll") for (int i = 0; i < 4; ++i) {                              \
      int c = i * 256 + t, rc = c & 127;                                         \
      gload_lds16(&Bt[(size_t)((NT)*32 + (rc >> 2)) * NC + (c >> 7) * 32 +       \
                      (rc & 3) * 8],                                             \
                  &Bl[DST][c * 8]);                                              \
    }                                                                            \
  }

#define P1_STEP(NT, CUR, GV)                                                     \
  {                                                                              \
    const int nt = (NT);                                                         \
    FV_STAGE(nt + 1, (CUR) ^ 1)                                                  \
    FV_MMA(CUR)                                                                  \
    float p0 = pn[nt * 32 + lm], p1 = pn[nt * 32 + 16 + lm];                     \
    _Pragma("unroll") for (int rg = 0; rg < 4; ++rg) {                           \
      float s0 = 2.0f * acc0[rg] - rnv[rg] - p0;                                 \
      float s1 = 2.0f * acc1[rg] - rnv[rg] - p1;                                 \
      float v0 = s0 + GV[rg * 2 + 0], v1 = s1 + GV[rg * 2 + 1];                  \
      if (v0 > bv_[rg]) { bv_[rg] = v0; bi_[rg] = nt * 32 + lm; }                \
      if (v1 > bv_[rg]) { bv_[rg] = v1; bi_[rg] = nt * 32 + 16 + lm; }           \
      float mt = fmaxf(s0, s1);                                                  \
      float zt = expf(s0 - mt) + expf(s1 - mt);                                  \
      float nm = fmaxf(m_[rg], mt);                                              \
      Z_[rg] = Z_[rg] * expf(m_[rg] - nm) + zt * expf(mt - nm);                  \
      m_[rg] = nm;                                                               \
    }                                                                            \
    __syncthreads();                                                             \
  }

#define G_ISSUE(NT, GV)                                                          \
  _Pragma("unroll") for (int rg = 0; rg < 4; ++rg) {                             \
    size_t gb = (size_t)(rbase + w * 16 + kq * 4 + rg) * NK + (NT)*32 + lm;      \
    GV[rg * 2 + 0] = gumbel[gb];                                                 \
    GV[rg * 2 + 1] = gumbel[gb + 16];                                            \
  }

  // ---- phase 1: online stats over 64 col-tiles (gumbel prefetch 4 ahead) ----
  float g0[8], g1[8], g2[8], g3[8];
  for (int it = 0; it < 16; ++it) {
    const int base = it * 4;
    G_ISSUE(base + 0, g0)
    G_ISSUE(base + 1, g1)
    G_ISSUE(base + 2, g2)
    G_ISSUE(base + 3, g3)
    P1_STEP(base + 0, 0, g0)
    P1_STEP(base + 1, 1, g1)
    P1_STEP(base + 2, 0, g2)
    P1_STEP(base + 3, 1, g3)
  }

  // final cross-lm combine (16 lanes per kq group hold the same rows)
#pragma unroll
  for (int rg = 0; rg < 4; ++rg) {
#pragma unroll
    for (int off = 1; off <= 8; off <<= 1) {
      float m2 = __shfl_xor(m_[rg], off);
      float Z2 = __shfl_xor(Z_[rg], off);
      float nm = fmaxf(m_[rg], m2);
      Z_[rg] = Z_[rg] * expf(m_[rg] - nm) + Z2 * expf(m2 - nm);
      m_[rg] = nm;
      float ov = __shfl_xor(bv_[rg], off);
      int oi = __shfl_xor(bi_[rg], off);
      if (ov > bv_[rg] || (ov == bv_[rg] && oi < bi_[rg])) { bv_[rg] = ov; bi_[rg] = oi; }
    }
  }
  float rZ_[4];
#pragma unroll
  for (int rg = 0; rg < 4; ++rg) rZ_[rg] = 1.0f / Z_[rg];
  float lsum = 0.f;
#pragma unroll
  for (int rg = 0; rg < 4; ++rg) lsum += m_[rg] + logf(Z_[rg]);
  lsum += __shfl_xor(lsum, 16);
  lsum += __shfl_xor(lsum, 32);  // = wave msum over its 16 rows

  // ---- gather argmax prototype rows -> out (bi staged via B-buffer LDS) ----
  int* bi_lds = (int*)Bl;
  if (lm == 0) {
#pragma unroll
    for (int rg = 0; rg < 4; ++rg) bi_lds[w * 16 + kq * 4 + rg] = bi_[rg];
  }
  __syncthreads();
#pragma unroll 4
  for (int r = 0; r < 64; ++r) {
    int b = bi_lds[r];
    out[(size_t)(rbase + r) * NC + t] = protos[(size_t)b * NC + t];
  }
  __syncthreads();

  // ---- phase 2: recompute s (identical accumulation order) -> colsums ----
#pragma unroll
  for (int i = 0; i < 4; ++i) {
    int c = i * 256 + t, rc = c & 127;
    gload_lds16(&Bt[(size_t)(rc >> 2) * NC + (c >> 7) * 32 + (rc & 3) * 8],
                &Bl[0][c * 8]);
  }
  __syncthreads();
  float* pp_w = pp + (size_t)(blockIdx.x * 4 + w) * NK;
  float* pl_w = pl + (size_t)(blockIdx.x * 4 + w) * NK;

#define P2_STEP(NT, CUR)                                                         \
  {                                                                              \
    const int nt = (NT);                                                         \
    FV_STAGE(nt + 1, (CUR) ^ 1)                                                  \
    FV_MMA(CUR)                                                                  \
    float p0 = pn[nt * 32 + lm], p1 = pn[nt * 32 + 16 + lm];                     \
    float ps0 = 0.f, ps1 = 0.f, ss0 = 0.f, ss1 = 0.f;                            \
    _Pragma("unroll") for (int rg = 0; rg < 4; ++rg) {                           \
      float s0 = 2.0f * acc0[rg] - rnv[rg] - p0;                                 \
      float s1 = 2.0f * acc1[rg] - rnv[rg] - p1;                                 \
      ps0 += expf(s0 - m_[rg]) * rZ_[rg];                                        \
      ps1 += expf(s1 - m_[rg]) * rZ_[rg];                                        \
      ss0 += s0; ss1 += s1;                                                      \
    }                                                                            \
    ps0 += __shfl_xor(ps0, 16); ps0 += __shfl_xor(ps0, 32);                      \
    ps1 += __shfl_xor(ps1, 16); ps1 += __shfl_xor(ps1, 32);                      \
    ss0 += __shfl_xor(ss0, 16); ss0 += __shfl_xor(ss0, 32);                      \
    ss1 += __shfl_xor(ss1, 16); ss1 += __shfl_xor(ss1, 32);                      \
    if (lane < 16) {                                                             \
      pp_w[nt * 32 + lane] = ps0;                                                \
      pp_w[nt * 32 + 16 + lane] = ps1;                                           \
      pl_w[nt * 32 + lane] = ss0 - lsum;                                         \
      pl_w[nt * 32 + 16 + lane] = ss1 - lsum;                                    \
    }                                                                            \
    __syncthreads();                                                             \
  }

  for (int it = 0; it < 32; ++it) {
    P2_STEP(it * 2 + 0, 0)
    P2_STEP(it * 2 + 1, 1)
  }
#undef P2_STEP
#undef G_ISSUE
#undef P1_STEP
#undef FV_STAGE
#undef FV_MMA
}

// ---------------------------------------------------------------------------
// Fold per-wave partials (1024 rows) into csp/csl. 64 blocks x 32 cols.
// ---------------------------------------------------------------------------
__global__ __launch_bounds__(256) void reduce_parts(const float* __restrict__ pp,
                                                    const float* __restrict__ pl,
                                                    float* __restrict__ csp,
                                                    float* __restrict__ csl) {
  const int t = threadIdx.x;
  const int col = blockIdx.x * 32 + (t & 31);
  const int grp = t >> 5;
  float a = 0.f, b = 0.f;
#pragma unroll 4
  for (int r = grp * 128; r < grp * 128 + 128; ++r) {
    a += pp[(size_t)r * NK + col];
    b += pl[(size_t)r * NK + col];
  }
  __shared__ float sa[8][32], sb[8][32];
  sa[grp][t & 31] = a;
  sb[grp][t & 31] = b;
  __syncthreads();
  if (t < 32) {
    float ra = 0.f, rb = 0.f;
#pragma unroll
    for (int gg = 0; gg < 8; ++gg) {
      ra += sa[gg][t];
      rb += sb[gg][t];
    }
    csp[blockIdx.x * 32 + t] = ra;
    csl[blockIdx.x * 32 + t] = rb;
  }
}

// ---------------------------------------------------------------------------
__global__ __launch_bounds__(256) void finalize_kernel(const float* __restrict__ csp,
                                                       const float* __restrict__ csl,
                                                       float* __restrict__ out_loss) {
  const int t = threadIdx.x;
  double cap = 0.0, plp = 0.0;
  for (int k = t; k < NK; k += 256) {
    float prior = csp[k] * (1.0f / (float)NB) + 1e-6f;
    float logprior = logf(prior);
    float mlp = csl[k] * (1.0f / (float)NB);
    cap += (double)prior * ((double)logprior - (double)mlp);
    plp += (double)prior * (double)logprior;
  }
  __shared__ double s1[256], s2[256];
  s1[t] = cap;
  s2[t] = plp;
  __syncthreads();
  for (int off = 128; off > 0; off >>= 1) {
    if (t < off) {
      s1[t] += s1[t + off];
      s2[t] += s2[t + off];
    }
    __syncthreads();
  }
  if (t == 0) out_loss[0] = (float)(0.01 * s1[0] + 0.001 * s2[0]);
}

// ---------------------------------------------------------------------------
extern "C" void kernel_launch(void* const* d_in, const int* in_sizes, int n_in,
                              void* d_out, int out_size, void* d_ws, size_t ws_size,
                              hipStream_t stream) {
  const float* x = (const float*)d_in[0];
  const float* gumbel = (const float*)d_in[1];
  const float* W_emb = (const float*)d_in[2];
  const float* b_emb = (const float*)d_in[3];
  const float* W0 = (const float*)d_in[4];
  const float* b0 = (const float*)d_in[5];
  const float* W1 = (const float*)d_in[6];
  const float* b1 = (const float*)d_in[7];
  const float* W_mu = (const float*)d_in[8];
  const float* b_mu = (const float*)d_in[9];
  // d_in[10]=W_var, d_in[11]=b_var unused (logvar dead downstream)
  const float* protos = (const float*)d_in[12];
  float* out = (float*)d_out;

  // workspace layout (offsets identical to the validated baseline; the S slot
  // is now unused but kept so all other offsets are unchanged)
  float* S = (float*)d_ws;                       // [NB][NK] fp32 (UNUSED now)
  float* rn = S + (size_t)NB * NK;               // [NB]
  float* pn = rn + NB;                           // [NK]
  float* csp = pn + NK;                          // [NK]
  float* csl = csp + NK;                         // [NK]
  bf16* xb = (bf16*)(csl + NK);                  // [NB][NDIN] = 16,777,216 B
  bf16* h0b = xb + (size_t)NB * NDIN;            // [NB][NH]
  bf16* h1b = h0b + (size_t)NB * NH;             // [NB][NH]
  bf16* h2b = h1b + (size_t)NB * NH;             // [NB][NC]
  bf16* mub = h2b + (size_t)NB * NC;             // [NB][NC]
  bf16* pb = mub + (size_t)NB * NC;              // [NK][NC]
  bf16* wembT = pb + (size_t)NK * NC;            // [NH][NDIN]
  bf16* w0T = wembT + NDIN * NH;                 // [NH][NH]
  bf16* w1T = w0T + NH * NH;                     // [NC][NH]
  bf16* wmuT = w1T + NH * NC;                    // [NC][NC]
  // pp/pl alias xb (dead after the first mfma_mlp; fused_vq runs strictly
  // later on the same stream). 2 * 1024 * 2048 * 4 B = 16,777,216 B == |xb|.
  float* pp = (float*)xb;                        // [1024][NK] partial probs
  float* pl = pp + (size_t)1024 * NK;            // [1024][NK] partial logprobs

  dim3 blk(256);
  cast_f2b<<<(NB * NDIN / 4 + 255) / 256, blk, 0, stream>>>(x, xb, NB * NDIN / 4);
  transpose_cast<<<(NDIN * NH + 255) / 256, blk, 0, stream>>>(W_emb, wembT, NDIN, NH);
  transpose_cast<<<(NH * NH + 255) / 256, blk, 0, stream>>>(W0, w0T, NH, NH);
  transpose_cast<<<(NH * NC + 255) / 256, blk, 0, stream>>>(W1, w1T, NH, NC);
  transpose_cast<<<(NC * NC + 255) / 256, blk, 0, stream>>>(W_mu, wmuT, NC, NC);
  cast_protos<<<NK / 4, blk, 0, stream>>>(protos, pb, pn);

  mfma_mlp<0><<<dim3(NB / 64, NH / 64), blk, 0, stream>>>(xb, wembT, b_emb, h0b, NB, NDIN, NH);
  mfma_mlp<1><<<dim3(NB / 64, NH / 64), blk, 0, stream>>>(h0b, w0T, b0, h1b, NB, NH, NH);
  mfma_mlp<1><<<dim3(NB / 64, NC / 64), blk, 0, stream>>>(h1b, w1T, b1, h2b, NB, NH, NC);
  mfma_mlp<0><<<dim3(NB / 64, NC / 64), blk, 0, stream>>>(h2b, wmuT, b_mu, mub, NB, NC, NC);

  rownorm_bf<<<NB / 4, blk, 0, stream>>>(mub, rn, NB);
  fused_vq<<<dim3(NB / 64), blk, 0, stream>>>(mub, pb, rn, pn, gumbel, protos, out, pp, pl);
  reduce_parts<<<dim3(NK / 32), blk, 0, stream>>>(pp, pl, csp, csl);
  finalize_kernel<<<1, blk, 0, stream>>>(csp, csl, out + (size_t)NB * NC);
}

// Round 8
// 347.873 us; speedup vs baseline: 1.3262x; 1.3262x over previous
//
#include <hip/hip_runtime.h>
#include <math.h>

// Problem constants (VQ2): B=16384, D_IN=512, H=64, C=256, K=2048
#define NB 16384
#define NDIN 512
#define NH 64
#define NC 256
#define NK 2048

// row_pass decomposition: 1024 blocks x 16 rows; whole block cooperates on
// each row (256 threads x 8 columns each).
#define RP_BLOCKS 1024
#define RP_ROWS_PER_BLOCK 16

typedef __bf16 bf16;
typedef __bf16 bf16x4 __attribute__((ext_vector_type(4)));
typedef __bf16 bf16x8 __attribute__((ext_vector_type(8)));
typedef float f32x4 __attribute__((ext_vector_type(4)));

__device__ __forceinline__ void gload_lds16(const bf16* g, bf16* l) {
  __builtin_amdgcn_global_load_lds(
      (const __attribute__((address_space(1))) void*)g,
      (__attribute__((address_space(3))) void*)l, 16, 0, 0);
}

// ---------------------------------------------------------------------------
// Elementwise fp32 -> bf16 cast (n4 = count/4)
// ---------------------------------------------------------------------------
__global__ __launch_bounds__(256) void cast_f2b(const float* __restrict__ in,
                                                bf16* __restrict__ out, int n4) {
  int i = blockIdx.x * 256 + threadIdx.x;
  if (i >= n4) return;
  float4 v = ((const float4*)in)[i];
  bf16x4 o;
  o[0] = (bf16)v.x; o[1] = (bf16)v.y; o[2] = (bf16)v.z; o[3] = (bf16)v.w;
  ((bf16x4*)out)[i] = o;
}

// ---------------------------------------------------------------------------
// Merged prep: 4 weight transposes (fp32 -> bf16, [K][N] -> [N][K]) + protos
// cast/norm, partitioned by blockIdx range. Math identical to the separate
// kernels it replaces (saves 4 launches).
//   blocks [0,128)   wembT  (K=512,N=64)
//   blocks [128,144) w0T    (K=64, N=64)
//   blocks [144,208) w1T    (K=64, N=256)
//   blocks [208,464) wmuT   (K=256,N=256)
//   blocks [464,976) protos cast + pn (4 waves/block, wave per proto row)
// ---------------------------------------------------------------------------
__global__ __launch_bounds__(256) void prep_small(
    const float* __restrict__ W_emb, const float* __restrict__ W0,
    const float* __restrict__ W1, const float* __restrict__ W_mu,
    const float* __restrict__ P,
    bf16* __restrict__ wembT, bf16* __restrict__ w0T, bf16* __restrict__ w1T,
    bf16* __restrict__ wmuT, bf16* __restrict__ Pb, float* __restrict__ pn) {
  const int b = blockIdx.x;
  const int t = threadIdx.x;
  if (b < 128) {                     // wembT: i over K*N = 512*64
    int i = b * 256 + t;
    int n = i / 512, k = i - n * 512;
    wembT[i] = (bf16)W_emb[k * 64 + n];
  } else if (b < 144) {              // w0T: 64*64
    int i = (b - 128) * 256 + t;
    int n = i / 64, k = i - n * 64;
    w0T[i] = (bf16)W0[k * 64 + n];
  } else if (b < 208) {              // w1T: K=64, N=256
    int i = (b - 144) * 256 + t;
    int n = i / 64, k = i - n * 64;
    w1T[i] = (bf16)W1[k * 256 + n];
  } else if (b < 464) {              // wmuT: 256*256
    int i = (b - 208) * 256 + t;
    int n = i / 256, k = i - n * 256;
    wmuT[i] = (bf16)W_mu[k * 256 + n];
  } else {                           // protos cast + pn (norm of ROUNDED values)
    int wave = (b - 464) * 4 + (t >> 6);
    int lane = t & 63;
    float4 v = ((const float4*)(P + (size_t)wave * NC))[lane];
    bf16x4 o;
    o[0] = (bf16)v.x; o[1] = (bf16)v.y; o[2] = (bf16)v.z; o[3] = (bf16)v.w;
    ((bf16x4*)(Pb + (size_t)wave * NC))[lane] = o;
    float s = 0.f;
#pragma unroll
    for (int j = 0; j < 4; ++j) {
      float f = (float)o[j];
      s = fmaf(f, f, s);
    }
    for (int off = 32; off > 0; off >>= 1) s += __shfl_xor(s, off);
    if (lane == 0) pn[wave] = s;
  }
}

// ---------------------------------------------------------------------------
// Row squared-norms of bf16 [rows][NC]; one wave per row.
// ---------------------------------------------------------------------------
__global__ __launch_bounds__(256) void rownorm_bf(const bf16* __restrict__ X,
                                                  float* __restrict__ out, int rows) {
  int wave = (int)((blockIdx.x * 256 + threadIdx.x) >> 6);
  int lane = threadIdx.x & 63;
  if (wave >= rows) return;
  bf16x4 v = ((const bf16x4*)(X + (size_t)wave * NC))[lane];
  float s = 0.f;
#pragma unroll
  for (int j = 0; j < 4; ++j) {
    float f = (float)v[j];
    s = fmaf(f, f, s);
  }
  for (int off = 32; off > 0; off >>= 1) s += __shfl_xor(s, off);
  if (lane == 0) out[wave] = s;
}

// ---------------------------------------------------------------------------
// MLP MFMA GEMM: out_bf16 = act(A @ Bt^T + bias)
//   A [M][K] bf16 row-major, Bt [N][K] bf16 row-major (pre-transposed weight)
//   BM=64, BN=64, BK=32; 4 waves, wave computes 64x16.
// ---------------------------------------------------------------------------
template <int RELU>
__global__ __launch_bounds__(256) void mfma_mlp(const bf16* __restrict__ A,
                                                const bf16* __restrict__ Bt,
                                                const float* __restrict__ bias,
                                                bf16* __restrict__ out,
                                                int M, int K, int N) {
  __shared__ __align__(16) bf16 As[64 * 32];
  __shared__ __align__(16) bf16 Bs[64 * 32];
  const int t = threadIdx.x;
  const int w = t >> 6, lane = t & 63;
  const int bm = blockIdx.x * 64, bn = blockIdx.y * 64;
  const int lm = lane & 15, kq = lane >> 4;
  const int r = t >> 2, seg = t & 3;
  f32x4 acc[4] = {};
  for (int k0 = 0; k0 < K; k0 += 32) {
    __syncthreads();
    *(uint4*)&As[r * 32 + seg * 8] = *(const uint4*)&A[(size_t)(bm + r) * K + k0 + seg * 8];
    *(uint4*)&Bs[r * 32 + seg * 8] = *(const uint4*)&Bt[(size_t)(bn + r) * K + k0 + seg * 8];
    __syncthreads();
    bf16x8 bfr = *(const bf16x8*)&Bs[(w * 16 + lm) * 32 + kq * 8];
#pragma unroll
    for (int mi = 0; mi < 4; ++mi) {
      bf16x8 afr = *(const bf16x8*)&As[(mi * 16 + lm) * 32 + kq * 8];
      acc[mi] = __builtin_amdgcn_mfma_f32_16x16x32_bf16(afr, bfr, acc[mi], 0, 0, 0);
    }
  }
  const int col = bn + w * 16 + lm;
  const float bv = bias[col];
#pragma unroll
  for (int mi = 0; mi < 4; ++mi) {
#pragma unroll
    for (int rg = 0; rg < 4; ++rg) {
      float v = acc[mi][rg] + bv;
      if (RELU) v = fmaxf(v, 0.f);
      out[(size_t)(bm + mi * 16 + kq * 4 + rg) * N + col] = (bf16)v;
    }
  }
}

// ---------------------------------------------------------------------------
// S-GEMM (MFMA): S[b][k] = 2*mu_bf[b]·p_bf[k] - rn[b] - pn[k]   (fp32 out)
//   128x128 tile, BK=32, global_load_lds width-16 staging (m97 structure).
// ---------------------------------------------------------------------------
__global__ __launch_bounds__(256) void gemm_S_mfma(const bf16* __restrict__ A,
                                                   const bf16* __restrict__ Bt,
                                                   const float* __restrict__ rn,
                                                   const float* __restrict__ pn,
                                                   float* __restrict__ S) {
  __shared__ __align__(16) bf16 As[128 * 32];
  __shared__ __align__(16) bf16 Bs[128 * 32];
  const int t = threadIdx.x;
  const int w = t >> 6, lane = t & 63;
  const int bm = blockIdx.x * 128, bn = blockIdx.y * 128;
  const int wm = (w >> 1) * 64, wn = (w & 1) * 64;
  const int lm = lane & 15, kq = lane >> 4;
  f32x4 acc[4][4] = {};
  for (int k0 = 0; k0 < NC; k0 += 32) {
    __syncthreads();
#pragma unroll
    for (int i = 0; i < 2; ++i) {
      int c = i * 256 + t;        // 16B chunk index; lds byte = c*16 (lane-contiguous)
      int r = c >> 2, seg = c & 3;
      gload_lds16(&A[(size_t)(bm + r) * NC + k0 + seg * 8], &As[c * 8]);
      gload_lds16(&Bt[(size_t)(bn + r) * NC + k0 + seg * 8], &Bs[c * 8]);
    }
    __syncthreads();
    bf16x8 a[4], b[4];
#pragma unroll
    for (int i = 0; i < 4; ++i) {
      a[i] = *(const bf16x8*)&As[(wm + i * 16 + lm) * 32 + kq * 8];
      b[i] = *(const bf16x8*)&Bs[(wn + i * 16 + lm) * 32 + kq * 8];
    }
#pragma unroll
    for (int mi = 0; mi < 4; ++mi)
#pragma unroll
      for (int ni = 0; ni < 4; ++ni)
        acc[mi][ni] = __builtin_amdgcn_mfma_f32_16x16x32_bf16(a[mi], b[ni], acc[mi][ni], 0, 0, 0);
  }
#pragma unroll
  for (int mi = 0; mi < 4; ++mi) {
#pragma unroll
    for (int rg = 0; rg < 4; ++rg) {
      int row = bm + wm + mi * 16 + kq * 4 + rg;
      float rv = rn[row];
#pragma unroll
      for (int ni = 0; ni < 4; ++ni) {
        int col = bn + wn + ni * 16 + lm;
        S[(size_t)row * NK + col] = 2.0f * acc[mi][ni][rg] - rv - pn[col];
      }
    }
  }
}

// ---------------------------------------------------------------------------
// Row pass: softmax stats + argmax(S+g) + proto gather + column sums.
// BLOCK-cooperative rows: 256 threads each own 8 columns of the 2048-col row
// (float4 at col 4t and col 1024+4t). Per-thread register state small ->
// no spill; exclusive column ownership -> no LDS combine, no atomics.
// Two __syncthreads per row (max/argmax and Z reductions, 4-slot exchange).
// Per-block partials to pp/pl. (Verified structure, 357us total in R5.)
// ---------------------------------------------------------------------------
__global__ __launch_bounds__(256) void row_pass(
    const float* __restrict__ S, const float* __restrict__ gumbel,
    const float* __restrict__ protos, float* __restrict__ out,
    float* __restrict__ pp, float* __restrict__ pl) {
  __shared__ float red_m[4], red_v[4], red_z[4];
  __shared__ int red_i[4];
  const int t = threadIdx.x;
  const int w = t >> 6, lane = t & 63;
  const int rbase = blockIdx.x * RP_ROWS_PER_BLOCK;
  const float4* S4 = (const float4*)S;
  const float4* G4 = (const float4*)gumbel;

  float4 pa0 = {}, pa1 = {}, la0 = {}, la1 = {};
  float msum = 0.f;  // block-uniform sum over rows of (m + logZ)

  float4 sA0, sA1, gA0, gA1, sB0, sB1, gB0, gB1;
  {
    size_t o = (size_t)rbase * (NK / 4) + t;
    sA0 = S4[o]; sA1 = S4[o + 256];
    gA0 = G4[o]; gA1 = G4[o + 256];
  }

#define RP_PROCESS(BROW, s0, s1, g0, g1)                                        \
  {                                                                             \
    float m = fmaxf(fmaxf(fmaxf(s0.x, s0.y), fmaxf(s0.z, s0.w)),                \
                    fmaxf(fmaxf(s1.x, s1.y), fmaxf(s1.z, s1.w)));               \
    float bv = s0.x + g0.x; int bi = t * 4;                                     \
    { float v = s0.y + g0.y; if (v > bv) { bv = v; bi = t * 4 + 1; } }          \
    { float v = s0.z + g0.z; if (v > bv) { bv = v; bi = t * 4 + 2; } }          \
    { float v = s0.w + g0.w; if (v > bv) { bv = v; bi = t * 4 + 3; } }          \
    { float v = s1.x + g1.x; if (v > bv) { bv = v; bi = 1024 + t * 4; } }       \
    { float v = s1.y + g1.y; if (v > bv) { bv = v; bi = 1024 + t * 4 + 1; } }   \
    { float v = s1.z + g1.z; if (v > bv) { bv = v; bi = 1024 + t * 4 + 2; } }   \
    { float v = s1.w + g1.w; if (v > bv) { bv = v; bi = 1024 + t * 4 + 3; } }   \
    for (int off = 32; off > 0; off >>= 1) {                                    \
      m = fmaxf(m, __shfl_xor(m, off));                                         \
      float ov = __shfl_xor(bv, off);                                           \
      int oi = __shfl_xor(bi, off);                                             \
      if (ov > bv || (ov == bv && oi < bi)) { bv = ov; bi = oi; }               \
    }                                                                           \
    if (lane == 0) { red_m[w] = m; red_v[w] = bv; red_i[w] = bi; }              \
    __syncthreads();                                                            \
    float M = fmaxf(fmaxf(red_m[0], red_m[1]), fmaxf(red_m[2], red_m[3]));      \
    float BV = red_v[0]; int BI = red_i[0];                                     \
    for (int ww = 1; ww < 4; ++ww) {                                            \
      float v = red_v[ww]; int i2 = red_i[ww];                                  \
      if (v > BV || (v == BV && i2 < BI)) { BV = v; BI = i2; }                  \
    }                                                                           \
    float4 e0, e1;                                                              \
    e0.x = expf(s0.x - M); e0.y = expf(s0.y - M);                               \
    e0.z = expf(s0.z - M); e0.w = expf(s0.w - M);                               \
    e1.x = expf(s1.x - M); e1.y = expf(s1.y - M);                               \
    e1.z = expf(s1.z - M); e1.w = expf(s1.w - M);                               \
    float z = ((e0.x + e0.y) + (e0.z + e0.w)) + ((e1.x + e1.y) + (e1.z + e1.w));\
    for (int off = 32; off > 0; off >>= 1) z += __shfl_xor(z, off);             \
    if (lane == 0) red_z[w] = z;                                                \
    __syncthreads();                                                            \
    float Z = (red_z[0] + red_z[1]) + (red_z[2] + red_z[3]);                    \
    float rz = 1.0f / Z;                                                        \
    pa0.x = fmaf(e0.x, rz, pa0.x); pa0.y = fmaf(e0.y, rz, pa0.y);               \
    pa0.z = fmaf(e0.z, rz, pa0.z); pa0.w = fmaf(e0.w, rz, pa0.w);               \
    pa1.x = fmaf(e1.x, rz, pa1.x); pa1.y = fmaf(e1.y, rz, pa1.y);               \
    pa1.z = fmaf(e1.z, rz, pa1.z); pa1.w = fmaf(e1.w, rz, pa1.w);               \
    la0.x += s0.x; la0.y += s0.y; la0.z += s0.z; la0.w += s0.w;                 \
    la1.x += s1.x; la1.y += s1.y; la1.z += s1.z; la1.w += s1.w;                 \
    msum += M + logf(Z);                                                        \
    out[(size_t)(BROW)*NC + t] = protos[(size_t)BI * NC + t];                   \
  }

  for (int r = 0; r < RP_ROWS_PER_BLOCK; r += 2) {
    {
      size_t o = (size_t)(rbase + r + 1) * (NK / 4) + t;
      sB0 = S4[o]; sB1 = S4[o + 256];
      gB0 = G4[o]; gB1 = G4[o + 256];
    }
    RP_PROCESS(rbase + r, sA0, sA1, gA0, gA1);
    if (r + 2 < RP_ROWS_PER_BLOCK) {
      size_t o = (size_t)(rbase + r + 2) * (NK / 4) + t;
      sA0 = S4[o]; sA1 = S4[o + 256];
      gA0 = G4[o]; gA1 = G4[o + 256];
    }
    RP_PROCESS(rbase + r + 1, sB0, sB1, gB0, gB1);
  }
#undef RP_PROCESS

  // per-block partials: thread t owns float4 cols [4t..4t+3] and [1024+4t..]
  float4* PP = (float4*)(pp + (size_t)blockIdx.x * NK);
  float4* PL = (float4*)(pl + (size_t)blockIdx.x * NK);
  PP[t] = pa0;
  PP[t + 256] = pa1;
  float4 l0, l1;
  l0.x = la0.x - msum; l0.y = la0.y - msum; l0.z = la0.z - msum; l0.w = la0.w - msum;
  l1.x = la1.x - msum; l1.y = la1.y - msum; l1.z = la1.z - msum; l1.w = la1.w - msum;
  PL[t] = l0;
  PL[t + 256] = l1;
}

// ---------------------------------------------------------------------------
// Fold per-block partials into csp/csl. 64 blocks; block handles 32 columns,
// 8 row-groups of 128 partial rows each (RP_BLOCKS=1024 rows total).
// ---------------------------------------------------------------------------
__global__ __launch_bounds__(256) void reduce_parts(const float* __restrict__ pp,
                                                    const float* __restrict__ pl,
                                                    float* __restrict__ csp,
                                                    float* __restrict__ csl) {
  const int t = threadIdx.x;
  const int col = blockIdx.x * 32 + (t & 31);
  const int grp = t >> 5;
  float a = 0.f, b = 0.f;
#pragma unroll 4
  for (int r = grp * 128; r < grp * 128 + 128; ++r) {
    a += pp[(size_t)r * NK + col];
    b += pl[(size_t)r * NK + col];
  }
  __shared__ float sa[8][32], sb[8][32];
  sa[grp][t & 31] = a;
  sb[grp][t & 31] = b;
  __syncthreads();
  if (t < 32) {
    float ra = 0.f, rb = 0.f;
#pragma unroll
    for (int gg = 0; gg < 8; ++gg) {
      ra += sa[gg][t];
      rb += sb[gg][t];
    }
    csp[blockIdx.x * 32 + t] = ra;
    csl[blockIdx.x * 32 + t] = rb;
  }
}

// ---------------------------------------------------------------------------
__global__ __launch_bounds__(256) void finalize_kernel(const float* __restrict__ csp,
                                                       const float* __restrict__ csl,
                                                       float* __restrict__ out_loss) {
  const int t = threadIdx.x;
  double cap = 0.0, plp = 0.0;
  for (int k = t; k < NK; k += 256) {
    float prior = csp[k] * (1.0f / (float)NB) + 1e-6f;
    float logprior = logf(prior);
    float mlp = csl[k] * (1.0f / (float)NB);
    cap += (double)prior * ((double)logprior - (double)mlp);
    plp += (double)prior * (double)logprior;
  }
  __shared__ double s1[256], s2[256];
  s1[t] = cap;
  s2[t] = plp;
  __syncthreads();
  for (int off = 128; off > 0; off >>= 1) {
    if (t < off) {
      s1[t] += s1[t + off];
      s2[t] += s2[t + off];
    }
    __syncthreads();
  }
  if (t == 0) out_loss[0] = (float)(0.01 * s1[0] + 0.001 * s2[0]);
}

// ---------------------------------------------------------------------------
extern "C" void kernel_launch(void* const* d_in, const int* in_sizes, int n_in,
                              void* d_out, int out_size, void* d_ws, size_t ws_size,
                              hipStream_t stream) {
  const float* x = (const float*)d_in[0];
  const float* gumbel = (const float*)d_in[1];
  const float* W_emb = (const float*)d_in[2];
  const float* b_emb = (const float*)d_in[3];
  const float* W0 = (const float*)d_in[4];
  const float* b0 = (const float*)d_in[5];
  const float* W1 = (const float*)d_in[6];
  const float* b1 = (const float*)d_in[7];
  const float* W_mu = (const float*)d_in[8];
  const float* b_mu = (const float*)d_in[9];
  // d_in[10]=W_var, d_in[11]=b_var unused (logvar dead downstream)
  const float* protos = (const float*)d_in[12];
  float* out = (float*)d_out;

  // workspace layout (byte-identical to the validated 357us R5 layout)
  float* S = (float*)d_ws;                       // [NB][NK] fp32
  float* rn = S + (size_t)NB * NK;               // [NB]
  float* pn = rn + NB;                           // [NK]
  float* csp = pn + NK;                          // [NK]
  float* csl = csp + NK;                         // [NK]
  bf16* xb = (bf16*)(csl + NK);                  // [NB][NDIN] = 16,777,216 B
  bf16* h0b = xb + (size_t)NB * NDIN;            // [NB][NH]
  bf16* h1b = h0b + (size_t)NB * NH;             // [NB][NH]
  bf16* h2b = h1b + (size_t)NB * NH;             // [NB][NC]
  bf16* mub = h2b + (size_t)NB * NC;             // [NB][NC]
  bf16* pb = mub + (size_t)NB * NC;              // [NK][NC]
  bf16* wembT = pb + (size_t)NK * NC;            // [NH][NDIN]
  bf16* w0T = wembT + NDIN * NH;                 // [NH][NH]
  bf16* w1T = w0T + NH * NH;                     // [NC][NH]
  bf16* wmuT = w1T + NH * NC;                    // [NC][NC]
  // pp/pl alias xb (dead after the first mfma_mlp; row_pass runs strictly
  // later on the same stream). 2 * 1024 * 2048 * 4 B = 16,777,216 B == |xb|.
  float* pp = (float*)xb;                        // [RP_BLOCKS][NK] partial probs
  float* pl = pp + (size_t)RP_BLOCKS * NK;       // [RP_BLOCKS][NK] partial logprobs

  dim3 blk(256);
  cast_f2b<<<(NB * NDIN / 4 + 255) / 256, blk, 0, stream>>>(x, xb, NB * NDIN / 4);
  prep_small<<<976, blk, 0, stream>>>(W_emb, W0, W1, W_mu, protos,
                                      wembT, w0T, w1T, wmuT, pb, pn);

  mfma_mlp<0><<<dim3(NB / 64, NH / 64), blk, 0, stream>>>(xb, wembT, b_emb, h0b, NB, NDIN, NH);
  mfma_mlp<1><<<dim3(NB / 64, NH / 64), blk, 0, stream>>>(h0b, w0T, b0, h1b, NB, NH, NH);
  mfma_mlp<1><<<dim3(NB / 64, NC / 64), blk, 0, stream>>>(h1b, w1T, b1, h2b, NB, NH, NC);
  mfma_mlp<0><<<dim3(NB / 64, NC / 64), blk, 0, stream>>>(h2b, wmuT, b_mu, mub, NB, NC, NC);

  rownorm_bf<<<NB / 4, blk, 0, stream>>>(mub, rn, NB);
  gemm_S_mfma<<<dim3(NB / 128, NK / 128), blk, 0, stream>>>(mub, pb, rn, pn, S);
  row_pass<<<dim3(RP_BLOCKS), blk, 0, stream>>>(S, gumbel, protos, out, pp, pl);
  reduce_parts<<<dim3(NK / 32), blk, 0, stream>>>(pp, pl, csp, csl);
  finalize_kernel<<<1, blk, 0, stream>>>(csp, csl, out + (size_t)NB * NC);
}